// Round 23
// baseline (50.829 us; speedup 1.0000x reference)
//
#include <hip/hip_runtime.h>
#include <hip/hip_bf16.h>

// AttentionHead: B=4, T=4096, D=1024, DA=64, scale = 1/96 folded into q.
// R23 = attn: pair-processing at NW=12 (3 waves/SIMD, cap 170). Peak regs
// ~160 (o32+k32+v32+s32+q16+misc) -> fits WITHOUT K-prefetch (dropped;
// was worth only 0.4us). 6 independent chains/SIMD vs R22's 4.
// proj/prep = R18/R20 verbatim.

#define T_SEQ 4096
#define NW 12   // attention waves per block (3/SIMD; unified-reg cap 170)

using bf16x8 = __bf16 __attribute__((ext_vector_type(8)));
using f32x16 = float __attribute__((ext_vector_type(16)));
using uint4v = unsigned int __attribute__((ext_vector_type(4)));

static constexpr float QSCALE = 1.4426950408889634f / 96.0f;

__device__ __forceinline__ unsigned short bf1(float v) {
    unsigned u = __builtin_bit_cast(unsigned, v);
    u += 0x7FFFu + ((u >> 16) & 1u);
    return (unsigned short)(u >> 16);
}
__device__ __forceinline__ unsigned cvt2(float lo, float hi) {
    unsigned r;
    asm("v_cvt_pk_bf16_f32 %0, %1, %2" : "=v"(r) : "v"(lo), "v"(hi));
    return r;
}
// v_permlane32_swap: ONLY safe when a,b hold DISTINCT values (see R8 note).
__device__ __forceinline__ void pswap(unsigned& a, unsigned& b) {
    asm volatile("v_permlane32_swap_b32 %0, %1" : "+v"(a), "+v"(b));
}
__device__ __forceinline__ float bflo(unsigned u) {
    return __builtin_bit_cast(float, u << 16);
}
__device__ __forceinline__ float bfhi(unsigned u) {
    return __builtin_bit_cast(float, u & 0xFFFF0000u);
}
__device__ __forceinline__ f32x16 zero16() {
    f32x16 z;
#pragma unroll
    for (int i = 0; i < 16; ++i) z[i] = 0.0f;
    return z;
}
#define MFMA32(a, b, c) __builtin_amdgcn_mfma_f32_32x32x16_bf16(a, b, c, 0, 0, 0)

// async global -> LDS, 16B per lane (dest = wave-uniform base + lane*16)
__device__ __forceinline__ void gload_lds16(const float* g, float* l) {
    __builtin_amdgcn_global_load_lds(
        (const __attribute__((address_space(1))) float*)g,
        (__attribute__((address_space(3))) float*)l, 16, 0, 0);
}

// ---------------- kernel 1: W -> Wt3 frag-linear bf16 ----------------
__global__ __launch_bounds__(256) void prep_w(
        const float* __restrict__ Wq, const float* __restrict__ Wk,
        const float* __restrict__ Wv, const float* __restrict__ bq,
        const float* __restrict__ bk, const float* __restrict__ bv,
        unsigned short* __restrict__ Wt3, float* __restrict__ bias_t) {
    __shared__ float tile[64][65];
    const int tid = threadIdx.x;
    const int m = blockIdx.x >> 4, kt = blockIdx.x & 15, d0 = kt * 64;
    const float* W = (m == 0) ? Wq : (m == 1) ? Wk : Wv;
    const int a = tid & 63, r4 = tid >> 6;
#pragma unroll
    for (int j = 0; j < 16; ++j) {
        const int rr = r4 + 4 * j;
        tile[rr][a] = W[(size_t)(d0 + rr) * 64 + a];
    }
    __syncthreads();
    const float scl = (m == 0) ? QSCALE : 1.0f;
    const int dc = tid & 63, ar = tid >> 6;
#pragma unroll
    for (int j = 0; j < 16; ++j) {
        const int aa = ar + 4 * j;
        const int cg = m * 64 + aa;
        const size_t addr =
            ((size_t)(kt * 6 + (cg >> 5)) * 4 + (dc >> 4)) * 512 +
            ((cg & 31) + 32 * ((dc >> 3) & 1)) * 8 + (dc & 7);
        Wt3[addr] = bf1(tile[dc][aa] * scl);
    }
    if (kt == 0 && tid < 64) {
        const float* bb = (m == 0) ? bq : (m == 1) ? bk : bv;
        bias_t[m * 64 + tid] = bb[tid] * scl;
    }
}

// ---------------- kernel 2: QKV projection (R18 verbatim) -----------------
__global__ __launch_bounds__(384, 3) void proj_kernel(
        const float* __restrict__ x, const unsigned short* __restrict__ Wt3,
        const float* __restrict__ bias_t, unsigned short* __restrict__ qs,
        unsigned short* __restrict__ ksf, unsigned short* __restrict__ vtf) {
    __shared__ float Ald[3][2048];   // [buf][32 rows x 64 f32] = 3 x 8 KB

    const int tid = threadIdx.x;
    const int w = tid >> 6, l = tid & 63, g = l >> 5, c32 = l & 31;
    const int ct = w;
    const int rowbase = blockIdx.x * 32;

    const int j1 = w;
    const int row1 = 4 * j1 + (l >> 4);
    const float* gp1 = x + (size_t)(rowbase + row1) * 1024 +
                       (((l & 15) ^ (row1 & 7)) << 2);
    const bool has2 = (w < 2);
    const int j2 = 6 + w;
    const int row2 = 4 * j2 + (l >> 4);
    const float* gp2 = x + (size_t)(rowbase + row2) * 1024 +
                       (((l & 15) ^ (row2 & 7)) << 2);

    const unsigned short* Wb = Wt3 + (size_t)(ct * 4) * 512 + l * 8;

    f32x16 acc = zero16();
    bf16x8 bA[4], bB[4];

    gload_lds16(gp1, &Ald[0][j1 * 256]);
    if (has2) gload_lds16(gp2, &Ald[0][j2 * 256]);
    gload_lds16(gp1 + 64, &Ald[1][j1 * 256]);
    if (has2) gload_lds16(gp2 + 64, &Ald[1][j2 * 256]);
#pragma unroll
    for (int f = 0; f < 4; ++f) bA[f] = *(const bf16x8*)(Wb + f * 512);
    if (has2) asm volatile("s_waitcnt vmcnt(6)" ::: "memory");
    else      asm volatile("s_waitcnt vmcnt(5)" ::: "memory");
    __builtin_amdgcn_s_barrier();
    __builtin_amdgcn_sched_barrier(0);

    auto STAGE = [&](bf16x8(&bc)[4], bf16x8(&bn)[4], int kt) {
        if (kt < 15) {
            const unsigned short* Wn = Wb + (size_t)(kt + 1) * 12288;
#pragma unroll
            for (int f = 0; f < 4; ++f) bn[f] = *(const bf16x8*)(Wn + f * 512);
        }
        if (kt < 14) {
            gload_lds16(gp1 + (kt + 2) * 64, &Ald[(kt + 2) % 3][j1 * 256]);
            if (has2)
                gload_lds16(gp2 + (kt + 2) * 64, &Ald[(kt + 2) % 3][j2 * 256]);
        }
        const float* A = Ald[kt % 3];
#pragma unroll
        for (int kk = 0; kk < 4; ++kk) {
            const int blk = kk * 4 + g * 2;
            float4 f0 = *(const float4*)(A + c32 * 64 + ((blk ^ (c32 & 7)) << 2));
            float4 f1 = *(const float4*)(A + c32 * 64 + (((blk + 1) ^ (c32 & 7)) << 2));
            uint4v ua;
            ua[0] = cvt2(f0.x, f0.y); ua[1] = cvt2(f0.z, f0.w);
            ua[2] = cvt2(f1.x, f1.y); ua[3] = cvt2(f1.z, f1.w);
            bf16x8 af = __builtin_bit_cast(bf16x8, ua);
            acc = MFMA32(af, bc[kk], acc);
        }
        if (kt < 14) {
            if (has2) asm volatile("s_waitcnt vmcnt(6) lgkmcnt(0)" ::: "memory");
            else      asm volatile("s_waitcnt vmcnt(5) lgkmcnt(0)" ::: "memory");
            __builtin_amdgcn_s_barrier();
            __builtin_amdgcn_sched_barrier(0);
        } else if (kt == 14) {
            asm volatile("s_waitcnt vmcnt(4) lgkmcnt(0)" ::: "memory");
            __builtin_amdgcn_s_barrier();
            __builtin_amdgcn_sched_barrier(0);
        }
    };

#pragma unroll
    for (int kt = 0; kt < 16; kt += 2) {
        STAGE(bA, bB, kt);
        STAGE(bB, bA, kt + 1);
    }

    const int cg = ct * 32 + c32;
    const float bias = bias_t[cg];
    const int mat = cg >> 6, cm = cg & 63;
    if (mat == 2) {
#pragma unroll
        for (int q4 = 0; q4 < 4; ++q4) {
            const int rowg = rowbase + 8 * q4 + 4 * g;
            const int b = rowg >> 12, tl = rowg & (T_SEQ - 1);
            const int ch = tl >> 5;
            const int f = (cm >> 5) * 2 + (q4 >> 1);
            const int lane = (cm & 31) + 32 * (q4 & 1);
            unsigned lo = cvt2(acc[4 * q4 + 0] + bias, acc[4 * q4 + 1] + bias);
            unsigned hi = cvt2(acc[4 * q4 + 2] + bias, acc[4 * q4 + 3] + bias);
            *(uint2*)(vtf + ((size_t)b * 128 + ch) * 2048 + f * 512 +
                      lane * 8 + 4 * g) = make_uint2(lo, hi);
        }
    } else if (mat == 1) {
#pragma unroll
        for (int r = 0; r < 16; ++r) {
            const int rowg = rowbase + (r & 3) + 8 * (r >> 2) + 4 * g;
            const int b = rowg >> 12, tl = rowg & (T_SEQ - 1);
            ksf[((size_t)b * 128 + (tl >> 5)) * 2048 + (cm >> 4) * 512 +
                ((tl & 31) + 32 * ((cm >> 3) & 1)) * 8 + (cm & 7)] =
                bf1(acc[r] + bias);
        }
    } else {
#pragma unroll
        for (int r = 0; r < 16; ++r) {
            const int rowg = rowbase + (r & 3) + 8 * (r >> 2) + 4 * g;
            qs[(size_t)rowg * 64 + cm] = bf1(acc[r] + bias);
        }
    }
}

// ---------------- kernel 3: causal flash attention (v5: pairs @ NW=12) ----
// 256 blocks x 768 thr (12 waves, 3/SIMD). Keys mod 12, pair = 2 chunks,
// self-contained (no K-prefetch: would bust the 170 cap).
__global__ __launch_bounds__(768, 3) void attn_kernel(
        const unsigned short* __restrict__ qs, const unsigned short* __restrict__ ksf,
        const unsigned short* __restrict__ vtf, float* __restrict__ out) {
    __shared__ unsigned short Osh[NW][32][66];
    __shared__ float msh[NW][32];
    __shared__ float ssh[NW][32];

    const int tid = threadIdx.x;
    const int w = tid >> 6, l = tid & 63, g = l >> 5, c32 = l & 31;
    const int b = blockIdx.x & 3;
    const int pid = blockIdx.x >> 2;

    for (int tt = 0; tt < 2; ++tt) {
        const int jt = tt ? pid : 127 - pid;
        const int qbase = jt * 32;

        const unsigned short* qp =
            qs + ((size_t)b * T_SEQ + qbase + c32) * 64 + g * 8;
        bf16x8 qf[4];
#pragma unroll
        for (int t = 0; t < 4; ++t) qf[t] = *(const bf16x8*)(qp + 16 * t);

        const unsigned short* pKc = ksf + ((size_t)b * 128 + w) * 2048 + l * 8;
        const unsigned short* pVc = vtf + ((size_t)b * 128 + w) * 2048 + l * 8;

        const int nch = (jt >= w) ? (jt - w) / NW + 1 : 0;
        const bool hasDiag = (jt >= w) && ((jt - w) % NW == 0);
        const int npair = nch >> 1;
        const bool tailOdd = (nch & 1) != 0;
        float m = -INFINITY, ssum = 0.0f;
        f32x16 o0 = zero16(), o1 = zero16();

        auto DEFER = [&](float pm) {
            if (!__all(pm <= m + 8.0f)) {
                float rmax = fmaxf(pm, __shfl_xor(pm, 32, 64));
                const float mn = fmaxf(m, rmax);
                const float alpha = exp2f(m - mn);
#pragma unroll
                for (int r = 0; r < 16; ++r) { o0[r] *= alpha; o1[r] *= alpha; }
                ssum *= alpha;
                m = mn;
            }
        };
        auto TREEMAX = [&](const f32x16& s) {
            float a0 = fmaxf(fmaxf(s[0], s[1]), fmaxf(s[2], s[3]));
            float a1 = fmaxf(fmaxf(s[4], s[5]), fmaxf(s[6], s[7]));
            float a2 = fmaxf(fmaxf(s[8], s[9]), fmaxf(s[10], s[11]));
            float a3 = fmaxf(fmaxf(s[12], s[13]), fmaxf(s[14], s[15]));
            return fmaxf(fmaxf(a0, a1), fmaxf(a2, a3));
        };
        auto EXPPACK = [&](const f32x16& s, bf16x8& pb0, bf16x8& pb1) {
            float p[16];
#pragma unroll
            for (int r = 0; r < 16; ++r) p[r] = exp2f(s[r] - m);
            float s0 = (p[0] + p[1]) + (p[2] + p[3]);
            float s1 = (p[4] + p[5]) + (p[6] + p[7]);
            float s2 = (p[8] + p[9]) + (p[10] + p[11]);
            float s3 = (p[12] + p[13]) + (p[14] + p[15]);
            ssum += (s0 + s1) + (s2 + s3);
            unsigned c01 = cvt2(p[0], p[1]), c23 = cvt2(p[2], p[3]);
            unsigned c45 = cvt2(p[4], p[5]), c67 = cvt2(p[6], p[7]);
            pswap(c01, c45); pswap(c23, c67);
            unsigned c89 = cvt2(p[8], p[9]), cab = cvt2(p[10], p[11]);
            unsigned ccd = cvt2(p[12], p[13]), cef = cvt2(p[14], p[15]);
            pswap(c89, ccd); pswap(cab, cef);
            uint4v u0; u0[0] = c01; u0[1] = c23; u0[2] = c45; u0[3] = c67;
            uint4v u1; u1[0] = c89; u1[1] = cab; u1[2] = ccd; u1[3] = cef;
            pb0 = __builtin_bit_cast(bf16x8, u0);
            pb1 = __builtin_bit_cast(bf16x8, u1);
        };

        for (int j = 0; j < npair; ++j) {
            bf16x8 kA[4], kB[4], vA[4], vB[4];
#pragma unroll
            for (int t = 0; t < 4; ++t) {
                kA[t] = *(const bf16x8*)(pKc + t * 512);
                kB[t] = *(const bf16x8*)(pKc + NW * 2048 + t * 512);
            }
#pragma unroll
            for (int f = 0; f < 4; ++f) {
                vA[f] = *(const bf16x8*)(pVc + f * 512);
                vB[f] = *(const bf16x8*)(pVc + NW * 2048 + f * 512);
            }
            pKc += 2 * NW * 2048;
            pVc += 2 * NW * 2048;
            f32x16 sa = zero16(), sb = zero16();
            __builtin_amdgcn_s_setprio(1);
#pragma unroll
            for (int t = 0; t < 4; ++t) {   // two independent QK chains
                sa = MFMA32(kA[t], qf[t], sa);
                sb = MFMA32(kB[t], qf[t], sb);
            }
            __builtin_amdgcn_s_setprio(0);
            if (hasDiag && !tailOdd && j == npair - 1) {   // b = last chunk
#pragma unroll
                for (int r = 0; r < 16; ++r) {
                    const int kl = (r & 3) + 8 * (r >> 2) + 4 * g;
                    if (kl > c32) sb[r] = -1e30f;
                }
            }
            DEFER(fmaxf(TREEMAX(sa), TREEMAX(sb)));
            bf16x8 pa0, pa1, pb0, pb1;
            EXPPACK(sa, pa0, pa1);
            EXPPACK(sb, pb0, pb1);
            __builtin_amdgcn_s_setprio(1);
            o0 = MFMA32(vA[0], pa0, o0);
            o1 = MFMA32(vA[2], pa0, o1);
            o0 = MFMA32(vA[1], pa1, o0);
            o1 = MFMA32(vA[3], pa1, o1);
            o0 = MFMA32(vB[0], pb0, o0);
            o1 = MFMA32(vB[2], pb0, o1);
            o0 = MFMA32(vB[1], pb1, o0);
            o1 = MFMA32(vB[3], pb1, o1);
            __builtin_amdgcn_s_setprio(0);
        }
        if (tailOdd) {   // final single chunk (diag iff hasDiag)
            bf16x8 kT[4], vT[4];
#pragma unroll
            for (int t = 0; t < 4; ++t) kT[t] = *(const bf16x8*)(pKc + t * 512);
#pragma unroll
            for (int f = 0; f < 4; ++f) vT[f] = *(const bf16x8*)(pVc + f * 512);
            f32x16 sa = zero16();
            __builtin_amdgcn_s_setprio(1);
#pragma unroll
            for (int t = 0; t < 4; ++t) sa = MFMA32(kT[t], qf[t], sa);
            __builtin_amdgcn_s_setprio(0);
            if (hasDiag) {
#pragma unroll
                for (int r = 0; r < 16; ++r) {
                    const int kl = (r & 3) + 8 * (r >> 2) + 4 * g;
                    if (kl > c32) sa[r] = -1e30f;
                }
            }
            DEFER(TREEMAX(sa));
            bf16x8 pa0, pa1;
            EXPPACK(sa, pa0, pa1);
            __builtin_amdgcn_s_setprio(1);
            o0 = MFMA32(vT[0], pa0, o0);
            o1 = MFMA32(vT[2], pa0, o1);
            o0 = MFMA32(vT[1], pa1, o0);
            o1 = MFMA32(vT[3], pa1, o1);
            __builtin_amdgcn_s_setprio(0);
        }
        ssum += __shfl_xor(ssum, 32, 64);

        if (l < 32) { msh[w][l] = m; ssh[w][l] = ssum; }
#pragma unroll
        for (int q4 = 0; q4 < 4; ++q4) {
            const int base = 8 * q4 + 4 * g;
            *(unsigned*)&Osh[w][c32][base]      = cvt2(o0[4 * q4], o0[4 * q4 + 1]);
            *(unsigned*)&Osh[w][c32][base + 2]  = cvt2(o0[4 * q4 + 2], o0[4 * q4 + 3]);
            *(unsigned*)&Osh[w][c32][base + 32] = cvt2(o1[4 * q4], o1[4 * q4 + 1]);
            *(unsigned*)&Osh[w][c32][base + 34] = cvt2(o1[4 * q4 + 2], o1[4 * q4 + 3]);
        }
        __syncthreads();

        if (tid < 512) {   // combine NW wave-partials (32 rows x 16 d-quads)
            const int qrow = tid >> 4, e4 = tid & 15;
            float M = -INFINITY;
            float mw[NW];
#pragma unroll
            for (int u = 0; u < NW; ++u) { mw[u] = msh[u][qrow]; M = fmaxf(M, mw[u]); }
            float den = 0.0f;
            float r0 = 0.f, r1 = 0.f, r2 = 0.f, r3 = 0.f;
#pragma unroll
            for (int u = 0; u < NW; ++u) {
                const float scu = exp2f(mw[u] - M);
                den += ssh[u][qrow] * scu;
                const unsigned ua = *(const unsigned*)&Osh[u][qrow][4 * e4];
                const unsigned ub = *(const unsigned*)&Osh[u][qrow][4 * e4 + 2];
                r0 += bflo(ua) * scu;
                r1 += bfhi(ua) * scu;
                r2 += bflo(ub) * scu;
                r3 += bfhi(ub) * scu;
            }
            const float inv = 1.0f / den;
            float4 st;
            st.x = r0 * inv; st.y = r1 * inv; st.z = r2 * inv; st.w = r3 * inv;
            *(float4*)(out + ((size_t)b * T_SEQ + qbase + qrow) * 64 + 4 * e4) = st;
        }
        __syncthreads();
    }
}

// ---------------- launch ----------------
extern "C" void kernel_launch(void* const* d_in, const int* in_sizes, int n_in,
                              void* d_out, int out_size, void* d_ws, size_t ws_size,
                              hipStream_t stream) {
    const float* x  = (const float*)d_in[0];
    const float* Wq = (const float*)d_in[1];
    const float* bq = (const float*)d_in[2];
    const float* Wk = (const float*)d_in[3];
    const float* bk = (const float*)d_in[4];
    const float* Wv = (const float*)d_in[5];
    const float* bv = (const float*)d_in[6];
    float* out = (float*)d_out;

    char* ws = (char*)d_ws;
    unsigned short* Wt3    = (unsigned short*)(ws);                 // 384 KB
    float*          bias_t = (float*)(ws + 393216);                 // 768 B
    unsigned short* qsb    = (unsigned short*)(ws + (1u << 20));    // 2 MB
    unsigned short* ksb    = (unsigned short*)(ws + (3u << 20));    // 2 MB
    unsigned short* vtb    = (unsigned short*)(ws + (5u << 20));    // 2 MB

    prep_w<<<48, 256, 0, stream>>>(Wq, Wk, Wv, bq, bk, bv, Wt3, bias_t);
    proj_kernel<<<512, 384, 0, stream>>>(x, Wt3, bias_t, qsb, ksb, vtb);
    attn_kernel<<<256, 768, 0, stream>>>(qsb, ksb, vtb, out);
}

// Round 24
// 48.056 us; speedup vs baseline: 1.0577x; 1.0577x over previous
//
#include <hip/hip_runtime.h>
#include <hip/hip_bf16.h>

// AttentionHead: B=4, T=4096, D=1024, DA=64, scale = 1/96 folded into q.
// R24 = R22 verbatim (best: 48.16us). Restores from R23's NW=12-pairs
// regression (register cap too tight). Pipeline: prep_w (W -> frag-linear
// bf16) -> proj (DMA-staged MFMA GEMM, counted vmcnt, 2 blocks/CU) ->
// attn (8-wave split-K flash, chunk pairs, K-prefetch, defer-max).

#define T_SEQ 4096
#define NW 8    // attention waves per block (2/SIMD; unified-reg cap 256)

using bf16x8 = __bf16 __attribute__((ext_vector_type(8)));
using f32x16 = float __attribute__((ext_vector_type(16)));
using uint4v = unsigned int __attribute__((ext_vector_type(4)));

static constexpr float QSCALE = 1.4426950408889634f / 96.0f;

__device__ __forceinline__ unsigned short bf1(float v) {
    unsigned u = __builtin_bit_cast(unsigned, v);
    u += 0x7FFFu + ((u >> 16) & 1u);
    return (unsigned short)(u >> 16);
}
__device__ __forceinline__ unsigned cvt2(float lo, float hi) {
    unsigned r;
    asm("v_cvt_pk_bf16_f32 %0, %1, %2" : "=v"(r) : "v"(lo), "v"(hi));
    return r;
}
// v_permlane32_swap: ONLY safe when a,b hold DISTINCT values (see R8 note).
__device__ __forceinline__ void pswap(unsigned& a, unsigned& b) {
    asm volatile("v_permlane32_swap_b32 %0, %1" : "+v"(a), "+v"(b));
}
__device__ __forceinline__ float bflo(unsigned u) {
    return __builtin_bit_cast(float, u << 16);
}
__device__ __forceinline__ float bfhi(unsigned u) {
    return __builtin_bit_cast(float, u & 0xFFFF0000u);
}
__device__ __forceinline__ f32x16 zero16() {
    f32x16 z;
#pragma unroll
    for (int i = 0; i < 16; ++i) z[i] = 0.0f;
    return z;
}
#define MFMA32(a, b, c) __builtin_amdgcn_mfma_f32_32x32x16_bf16(a, b, c, 0, 0, 0)

// async global -> LDS, 16B per lane (dest = wave-uniform base + lane*16)
__device__ __forceinline__ void gload_lds16(const float* g, float* l) {
    __builtin_amdgcn_global_load_lds(
        (const __attribute__((address_space(1))) float*)g,
        (__attribute__((address_space(3))) float*)l, 16, 0, 0);
}

// ---------------- kernel 1: W -> Wt3 frag-linear bf16 ----------------
__global__ __launch_bounds__(256) void prep_w(
        const float* __restrict__ Wq, const float* __restrict__ Wk,
        const float* __restrict__ Wv, const float* __restrict__ bq,
        const float* __restrict__ bk, const float* __restrict__ bv,
        unsigned short* __restrict__ Wt3, float* __restrict__ bias_t) {
    __shared__ float tile[64][65];
    const int tid = threadIdx.x;
    const int m = blockIdx.x >> 4, kt = blockIdx.x & 15, d0 = kt * 64;
    const float* W = (m == 0) ? Wq : (m == 1) ? Wk : Wv;
    const int a = tid & 63, r4 = tid >> 6;
#pragma unroll
    for (int j = 0; j < 16; ++j) {
        const int rr = r4 + 4 * j;
        tile[rr][a] = W[(size_t)(d0 + rr) * 64 + a];
    }
    __syncthreads();
    const float scl = (m == 0) ? QSCALE : 1.0f;
    const int dc = tid & 63, ar = tid >> 6;
#pragma unroll
    for (int j = 0; j < 16; ++j) {
        const int aa = ar + 4 * j;
        const int cg = m * 64 + aa;
        const size_t addr =
            ((size_t)(kt * 6 + (cg >> 5)) * 4 + (dc >> 4)) * 512 +
            ((cg & 31) + 32 * ((dc >> 3) & 1)) * 8 + (dc & 7);
        Wt3[addr] = bf1(tile[dc][aa] * scl);
    }
    if (kt == 0 && tid < 64) {
        const float* bb = (m == 0) ? bq : (m == 1) ? bk : bv;
        bias_t[m * 64 + tid] = bb[tid] * scl;
    }
}

// ---------------- kernel 2: QKV projection (R18 structure) ----------------
__global__ __launch_bounds__(384, 3) void proj_kernel(
        const float* __restrict__ x, const unsigned short* __restrict__ Wt3,
        const float* __restrict__ bias_t, unsigned short* __restrict__ qs,
        unsigned short* __restrict__ ksf, unsigned short* __restrict__ vtf) {
    __shared__ float Ald[3][2048];   // [buf][32 rows x 64 f32] = 3 x 8 KB

    const int tid = threadIdx.x;
    const int w = tid >> 6, l = tid & 63, g = l >> 5, c32 = l & 31;
    const int ct = w;
    const int rowbase = blockIdx.x * 32;

    const int j1 = w;
    const int row1 = 4 * j1 + (l >> 4);
    const float* gp1 = x + (size_t)(rowbase + row1) * 1024 +
                       (((l & 15) ^ (row1 & 7)) << 2);
    const bool has2 = (w < 2);
    const int j2 = 6 + w;
    const int row2 = 4 * j2 + (l >> 4);
    const float* gp2 = x + (size_t)(rowbase + row2) * 1024 +
                       (((l & 15) ^ (row2 & 7)) << 2);

    const unsigned short* Wb = Wt3 + (size_t)(ct * 4) * 512 + l * 8;

    f32x16 acc = zero16();
    bf16x8 bA[4], bB[4];

    gload_lds16(gp1, &Ald[0][j1 * 256]);
    if (has2) gload_lds16(gp2, &Ald[0][j2 * 256]);
    gload_lds16(gp1 + 64, &Ald[1][j1 * 256]);
    if (has2) gload_lds16(gp2 + 64, &Ald[1][j2 * 256]);
#pragma unroll
    for (int f = 0; f < 4; ++f) bA[f] = *(const bf16x8*)(Wb + f * 512);
    if (has2) asm volatile("s_waitcnt vmcnt(6)" ::: "memory");
    else      asm volatile("s_waitcnt vmcnt(5)" ::: "memory");
    __builtin_amdgcn_s_barrier();
    __builtin_amdgcn_sched_barrier(0);

    auto STAGE = [&](bf16x8(&bc)[4], bf16x8(&bn)[4], int kt) {
        if (kt < 15) {
            const unsigned short* Wn = Wb + (size_t)(kt + 1) * 12288;
#pragma unroll
            for (int f = 0; f < 4; ++f) bn[f] = *(const bf16x8*)(Wn + f * 512);
        }
        if (kt < 14) {
            gload_lds16(gp1 + (kt + 2) * 64, &Ald[(kt + 2) % 3][j1 * 256]);
            if (has2)
                gload_lds16(gp2 + (kt + 2) * 64, &Ald[(kt + 2) % 3][j2 * 256]);
        }
        const float* A = Ald[kt % 3];
#pragma unroll
        for (int kk = 0; kk < 4; ++kk) {
            const int blk = kk * 4 + g * 2;
            float4 f0 = *(const float4*)(A + c32 * 64 + ((blk ^ (c32 & 7)) << 2));
            float4 f1 = *(const float4*)(A + c32 * 64 + (((blk + 1) ^ (c32 & 7)) << 2));
            uint4v ua;
            ua[0] = cvt2(f0.x, f0.y); ua[1] = cvt2(f0.z, f0.w);
            ua[2] = cvt2(f1.x, f1.y); ua[3] = cvt2(f1.z, f1.w);
            bf16x8 af = __builtin_bit_cast(bf16x8, ua);
            acc = MFMA32(af, bc[kk], acc);
        }
        if (kt < 14) {
            if (has2) asm volatile("s_waitcnt vmcnt(6) lgkmcnt(0)" ::: "memory");
            else      asm volatile("s_waitcnt vmcnt(5) lgkmcnt(0)" ::: "memory");
            __builtin_amdgcn_s_barrier();
            __builtin_amdgcn_sched_barrier(0);
        } else if (kt == 14) {
            asm volatile("s_waitcnt vmcnt(4) lgkmcnt(0)" ::: "memory");
            __builtin_amdgcn_s_barrier();
            __builtin_amdgcn_sched_barrier(0);
        }
    };

#pragma unroll
    for (int kt = 0; kt < 16; kt += 2) {
        STAGE(bA, bB, kt);
        STAGE(bB, bA, kt + 1);
    }

    const int cg = ct * 32 + c32;
    const float bias = bias_t[cg];
    const int mat = cg >> 6, cm = cg & 63;
    if (mat == 2) {
#pragma unroll
        for (int q4 = 0; q4 < 4; ++q4) {
            const int rowg = rowbase + 8 * q4 + 4 * g;
            const int b = rowg >> 12, tl = rowg & (T_SEQ - 1);
            const int ch = tl >> 5;
            const int f = (cm >> 5) * 2 + (q4 >> 1);
            const int lane = (cm & 31) + 32 * (q4 & 1);
            unsigned lo = cvt2(acc[4 * q4 + 0] + bias, acc[4 * q4 + 1] + bias);
            unsigned hi = cvt2(acc[4 * q4 + 2] + bias, acc[4 * q4 + 3] + bias);
            *(uint2*)(vtf + ((size_t)b * 128 + ch) * 2048 + f * 512 +
                      lane * 8 + 4 * g) = make_uint2(lo, hi);
        }
    } else if (mat == 1) {
#pragma unroll
        for (int r = 0; r < 16; ++r) {
            const int rowg = rowbase + (r & 3) + 8 * (r >> 2) + 4 * g;
            const int b = rowg >> 12, tl = rowg & (T_SEQ - 1);
            ksf[((size_t)b * 128 + (tl >> 5)) * 2048 + (cm >> 4) * 512 +
                ((tl & 31) + 32 * ((cm >> 3) & 1)) * 8 + (cm & 7)] =
                bf1(acc[r] + bias);
        }
    } else {
#pragma unroll
        for (int r = 0; r < 16; ++r) {
            const int rowg = rowbase + (r & 3) + 8 * (r >> 2) + 4 * g;
            qs[(size_t)rowg * 64 + cm] = bf1(acc[r] + bias);
        }
    }
}

// ---------------- kernel 3: causal flash attention (R22 structure) --------
// 256 blocks x 512 thr (8 waves, 2/SIMD). Keys mod 8, pair = 2 chunks.
// Next pair's K prefetched (+32 VGPR) during softmax+PV; V single-buffered.
__global__ __launch_bounds__(512, 2) void attn_kernel(
        const unsigned short* __restrict__ qs, const unsigned short* __restrict__ ksf,
        const unsigned short* __restrict__ vtf, float* __restrict__ out) {
    __shared__ unsigned short Osh[NW][32][66];
    __shared__ float msh[NW][32];
    __shared__ float ssh[NW][32];

    const int tid = threadIdx.x;
    const int w = tid >> 6, l = tid & 63, g = l >> 5, c32 = l & 31;
    const int b = blockIdx.x & 3;
    const int pid = blockIdx.x >> 2;

    for (int tt = 0; tt < 2; ++tt) {
        const int jt = tt ? pid : 127 - pid;
        const int qbase = jt * 32;

        const unsigned short* qp =
            qs + ((size_t)b * T_SEQ + qbase + c32) * 64 + g * 8;
        bf16x8 qf[4];
#pragma unroll
        for (int t = 0; t < 4; ++t) qf[t] = *(const bf16x8*)(qp + 16 * t);

        const unsigned short* pKc = ksf + ((size_t)b * 128 + w) * 2048 + l * 8;
        const unsigned short* pVc = vtf + ((size_t)b * 128 + w) * 2048 + l * 8;

        const int nch = (jt >= w) ? (jt - w) / NW + 1 : 0;
        const bool hasDiag = (jt >= w) && ((jt - w) % NW == 0);
        const int npair = nch >> 1;
        const bool tailOdd = (nch & 1) != 0;
        float m = -INFINITY, ssum = 0.0f;
        f32x16 o0 = zero16(), o1 = zero16();

        auto LOADK = [&](bf16x8(&kA)[4], bf16x8(&kB)[4]) {
#pragma unroll
            for (int t = 0; t < 4; ++t) {
                kA[t] = *(const bf16x8*)(pKc + t * 512);
                kB[t] = *(const bf16x8*)(pKc + NW * 2048 + t * 512);
            }
            pKc += 2 * NW * 2048;
        };
        auto DEFER = [&](float pm) {
            if (!__all(pm <= m + 8.0f)) {
                float rmax = fmaxf(pm, __shfl_xor(pm, 32, 64));
                const float mn = fmaxf(m, rmax);
                const float alpha = exp2f(m - mn);
#pragma unroll
                for (int r = 0; r < 16; ++r) { o0[r] *= alpha; o1[r] *= alpha; }
                ssum *= alpha;
                m = mn;
            }
        };
        auto TREEMAX = [&](const f32x16& s) {
            float a0 = fmaxf(fmaxf(s[0], s[1]), fmaxf(s[2], s[3]));
            float a1 = fmaxf(fmaxf(s[4], s[5]), fmaxf(s[6], s[7]));
            float a2 = fmaxf(fmaxf(s[8], s[9]), fmaxf(s[10], s[11]));
            float a3 = fmaxf(fmaxf(s[12], s[13]), fmaxf(s[14], s[15]));
            return fmaxf(fmaxf(a0, a1), fmaxf(a2, a3));
        };
        auto EXPPACK = [&](const f32x16& s, bf16x8& pb0, bf16x8& pb1) {
            float p[16];
#pragma unroll
            for (int r = 0; r < 16; ++r) p[r] = exp2f(s[r] - m);
            float s0 = (p[0] + p[1]) + (p[2] + p[3]);
            float s1 = (p[4] + p[5]) + (p[6] + p[7]);
            float s2 = (p[8] + p[9]) + (p[10] + p[11]);
            float s3 = (p[12] + p[13]) + (p[14] + p[15]);
            ssum += (s0 + s1) + (s2 + s3);
            unsigned c01 = cvt2(p[0], p[1]), c23 = cvt2(p[2], p[3]);
            unsigned c45 = cvt2(p[4], p[5]), c67 = cvt2(p[6], p[7]);
            pswap(c01, c45); pswap(c23, c67);
            unsigned c89 = cvt2(p[8], p[9]), cab = cvt2(p[10], p[11]);
            unsigned ccd = cvt2(p[12], p[13]), cef = cvt2(p[14], p[15]);
            pswap(c89, ccd); pswap(cab, cef);
            uint4v u0; u0[0] = c01; u0[1] = c23; u0[2] = c45; u0[3] = c67;
            uint4v u1; u1[0] = c89; u1[1] = cab; u1[2] = ccd; u1[3] = cef;
            pb0 = __builtin_bit_cast(bf16x8, u0);
            pb1 = __builtin_bit_cast(bf16x8, u1);
        };

        bf16x8 kA0[4], kB0[4], kA1[4], kB1[4];   // K pair double-buffer
        if (npair > 0) LOADK(kA0, kB0);

        auto PAIR = [&](bf16x8(&kA)[4], bf16x8(&kB)[4],
                        bf16x8(&nkA)[4], bf16x8(&nkB)[4], int j) {
            bf16x8 vA[4], vB[4];
#pragma unroll
            for (int f = 0; f < 4; ++f) {
                vA[f] = *(const bf16x8*)(pVc + f * 512);
                vB[f] = *(const bf16x8*)(pVc + NW * 2048 + f * 512);
            }
            pVc += 2 * NW * 2048;
            f32x16 sa = zero16(), sb = zero16();
            __builtin_amdgcn_s_setprio(1);
#pragma unroll
            for (int t = 0; t < 4; ++t) {
                sa = MFMA32(kA[t], qf[t], sa);
                sb = MFMA32(kB[t], qf[t], sb);
            }
            __builtin_amdgcn_s_setprio(0);
            if (j + 1 < npair) LOADK(nkA, nkB);
            if (hasDiag && !tailOdd && j == npair - 1) {
#pragma unroll
                for (int r = 0; r < 16; ++r) {
                    const int kl = (r & 3) + 8 * (r >> 2) + 4 * g;
                    if (kl > c32) sb[r] = -1e30f;
                }
            }
            DEFER(fmaxf(TREEMAX(sa), TREEMAX(sb)));
            bf16x8 pa0, pa1, pb0, pb1;
            EXPPACK(sa, pa0, pa1);
            EXPPACK(sb, pb0, pb1);
            __builtin_amdgcn_s_setprio(1);
            o0 = MFMA32(vA[0], pa0, o0);
            o1 = MFMA32(vA[2], pa0, o1);
            o0 = MFMA32(vA[1], pa1, o0);
            o1 = MFMA32(vA[3], pa1, o1);
            o0 = MFMA32(vB[0], pb0, o0);
            o1 = MFMA32(vB[2], pb0, o1);
            o0 = MFMA32(vB[1], pb1, o0);
            o1 = MFMA32(vB[3], pb1, o1);
            __builtin_amdgcn_s_setprio(0);
        };

        int j = 0;
        while (j < npair) {
            PAIR(kA0, kB0, kA1, kB1, j); ++j;
            if (j < npair) { PAIR(kA1, kB1, kA0, kB0, j); ++j; }
        }
        if (tailOdd) {
            bf16x8 kT[4], vT[4];
#pragma unroll
            for (int t = 0; t < 4; ++t) kT[t] = *(const bf16x8*)(pKc + t * 512);
#pragma unroll
            for (int f = 0; f < 4; ++f) vT[f] = *(const bf16x8*)(pVc + f * 512);
            f32x16 sa = zero16();
            __builtin_amdgcn_s_setprio(1);
#pragma unroll
            for (int t = 0; t < 4; ++t) sa = MFMA32(kT[t], qf[t], sa);
            __builtin_amdgcn_s_setprio(0);
            if (hasDiag) {
#pragma unroll
                for (int r = 0; r < 16; ++r) {
                    const int kl = (r & 3) + 8 * (r >> 2) + 4 * g;
                    if (kl > c32) sa[r] = -1e30f;
                }
            }
            DEFER(TREEMAX(sa));
            bf16x8 pa0, pa1;
            EXPPACK(sa, pa0, pa1);
            __builtin_amdgcn_s_setprio(1);
            o0 = MFMA32(vT[0], pa0, o0);
            o1 = MFMA32(vT[2], pa0, o1);
            o0 = MFMA32(vT[1], pa1, o0);
            o1 = MFMA32(vT[3], pa1, o1);
            __builtin_amdgcn_s_setprio(0);
        }
        ssum += __shfl_xor(ssum, 32, 64);

        if (l < 32) { msh[w][l] = m; ssh[w][l] = ssum; }
#pragma unroll
        for (int q4 = 0; q4 < 4; ++q4) {
            const int base = 8 * q4 + 4 * g;
            *(unsigned*)&Osh[w][c32][base]      = cvt2(o0[4 * q4], o0[4 * q4 + 1]);
            *(unsigned*)&Osh[w][c32][base + 2]  = cvt2(o0[4 * q4 + 2], o0[4 * q4 + 3]);
            *(unsigned*)&Osh[w][c32][base + 32] = cvt2(o1[4 * q4], o1[4 * q4 + 1]);
            *(unsigned*)&Osh[w][c32][base + 34] = cvt2(o1[4 * q4 + 2], o1[4 * q4 + 3]);
        }
        __syncthreads();

        {   // combine NW wave-partials (512 thr: 32 rows x 16 d-quads)
            const int qrow = tid >> 4, e4 = tid & 15;
            float M = -INFINITY;
            float mw[NW];
#pragma unroll
            for (int u = 0; u < NW; ++u) { mw[u] = msh[u][qrow]; M = fmaxf(M, mw[u]); }
            float den = 0.0f;
            float r0 = 0.f, r1 = 0.f, r2 = 0.f, r3 = 0.f;
#pragma unroll
            for (int u = 0; u < NW; ++u) {
                const float scu = exp2f(mw[u] - M);
                den += ssh[u][qrow] * scu;
                const unsigned ua = *(const unsigned*)&Osh[u][qrow][4 * e4];
                const unsigned ub = *(const unsigned*)&Osh[u][qrow][4 * e4 + 2];
                r0 += bflo(ua) * scu;
                r1 += bfhi(ua) * scu;
                r2 += bflo(ub) * scu;
                r3 += bfhi(ub) * scu;
            }
            const float inv = 1.0f / den;
            float4 st;
            st.x = r0 * inv; st.y = r1 * inv; st.z = r2 * inv; st.w = r3 * inv;
            *(float4*)(out + ((size_t)b * T_SEQ + qbase + qrow) * 64 + 4 * e4) = st;
        }
        __syncthreads();
    }
}

// ---------------- launch ----------------
extern "C" void kernel_launch(void* const* d_in, const int* in_sizes, int n_in,
                              void* d_out, int out_size, void* d_ws, size_t ws_size,
                              hipStream_t stream) {
    const float* x  = (const float*)d_in[0];
    const float* Wq = (const float*)d_in[1];
    const float* bq = (const float*)d_in[2];
    const float* Wk = (const float*)d_in[3];
    const float* bk = (const float*)d_in[4];
    const float* Wv = (const float*)d_in[5];
    const float* bv = (const float*)d_in[6];
    float* out = (float*)d_out;

    char* ws = (char*)d_ws;
    unsigned short* Wt3    = (unsigned short*)(ws);                 // 384 KB
    float*          bias_t = (float*)(ws + 393216);                 // 768 B
    unsigned short* qsb    = (unsigned short*)(ws + (1u << 20));    // 2 MB
    unsigned short* ksb    = (unsigned short*)(ws + (3u << 20));    // 2 MB
    unsigned short* vtb    = (unsigned short*)(ws + (5u << 20));    // 2 MB

    prep_w<<<48, 256, 0, stream>>>(Wq, Wk, Wv, bq, bk, bv, Wt3, bias_t);
    proj_kernel<<<512, 384, 0, stream>>>(x, Wt3, bias_t, qsb, ksb, vtb);
    attn_kernel<<<256, 512, 0, stream>>>(qsb, ksb, vtb, out);
}

// Round 25
// 48.045 us; speedup vs baseline: 1.0579x; 1.0002x over previous
//
#include <hip/hip_runtime.h>
#include <hip/hip_bf16.h>

// AttentionHead: B=4, T=4096, D=1024, DA=64, scale = 1/96 folded into q.
// R25 = R24 + proj DMA depth 2->3 (4 LDS buffers, 32KB/block). Barrier at
// stage kt previously proved DMA(kt+1) issued only ~1 stage (~1300cy) ago
// vs ~900-1100cy loaded-HBM latency - marginal cover, and any excursion
// stalls all 6 waves. Waits re-derived (in-order vmcnt retirement, issue
// order [B(kt+1)x4, D(kt+3)xc]): kt<=12: 2c+8; kt=13: c+8; kt=14: 8;
// prologue: 2c+4. attn/prep = R24 verbatim.

#define T_SEQ 4096
#define NW 8    // attention waves per block (2/SIMD; unified-reg cap 256)

using bf16x8 = __bf16 __attribute__((ext_vector_type(8)));
using f32x16 = float __attribute__((ext_vector_type(16)));
using uint4v = unsigned int __attribute__((ext_vector_type(4)));

static constexpr float QSCALE = 1.4426950408889634f / 96.0f;

__device__ __forceinline__ unsigned short bf1(float v) {
    unsigned u = __builtin_bit_cast(unsigned, v);
    u += 0x7FFFu + ((u >> 16) & 1u);
    return (unsigned short)(u >> 16);
}
__device__ __forceinline__ unsigned cvt2(float lo, float hi) {
    unsigned r;
    asm("v_cvt_pk_bf16_f32 %0, %1, %2" : "=v"(r) : "v"(lo), "v"(hi));
    return r;
}
// v_permlane32_swap: ONLY safe when a,b hold DISTINCT values (see R8 note).
__device__ __forceinline__ void pswap(unsigned& a, unsigned& b) {
    asm volatile("v_permlane32_swap_b32 %0, %1" : "+v"(a), "+v"(b));
}
__device__ __forceinline__ float bflo(unsigned u) {
    return __builtin_bit_cast(float, u << 16);
}
__device__ __forceinline__ float bfhi(unsigned u) {
    return __builtin_bit_cast(float, u & 0xFFFF0000u);
}
__device__ __forceinline__ f32x16 zero16() {
    f32x16 z;
#pragma unroll
    for (int i = 0; i < 16; ++i) z[i] = 0.0f;
    return z;
}
#define MFMA32(a, b, c) __builtin_amdgcn_mfma_f32_32x32x16_bf16(a, b, c, 0, 0, 0)

// async global -> LDS, 16B per lane (dest = wave-uniform base + lane*16)
__device__ __forceinline__ void gload_lds16(const float* g, float* l) {
    __builtin_amdgcn_global_load_lds(
        (const __attribute__((address_space(1))) float*)g,
        (__attribute__((address_space(3))) float*)l, 16, 0, 0);
}

// ---------------- kernel 1: W -> Wt3 frag-linear bf16 ----------------
__global__ __launch_bounds__(256) void prep_w(
        const float* __restrict__ Wq, const float* __restrict__ Wk,
        const float* __restrict__ Wv, const float* __restrict__ bq,
        const float* __restrict__ bk, const float* __restrict__ bv,
        unsigned short* __restrict__ Wt3, float* __restrict__ bias_t) {
    __shared__ float tile[64][65];
    const int tid = threadIdx.x;
    const int m = blockIdx.x >> 4, kt = blockIdx.x & 15, d0 = kt * 64;
    const float* W = (m == 0) ? Wq : (m == 1) ? Wk : Wv;
    const int a = tid & 63, r4 = tid >> 6;
#pragma unroll
    for (int j = 0; j < 16; ++j) {
        const int rr = r4 + 4 * j;
        tile[rr][a] = W[(size_t)(d0 + rr) * 64 + a];
    }
    __syncthreads();
    const float scl = (m == 0) ? QSCALE : 1.0f;
    const int dc = tid & 63, ar = tid >> 6;
#pragma unroll
    for (int j = 0; j < 16; ++j) {
        const int aa = ar + 4 * j;
        const int cg = m * 64 + aa;
        const size_t addr =
            ((size_t)(kt * 6 + (cg >> 5)) * 4 + (dc >> 4)) * 512 +
            ((cg & 31) + 32 * ((dc >> 3) & 1)) * 8 + (dc & 7);
        Wt3[addr] = bf1(tile[dc][aa] * scl);
    }
    if (kt == 0 && tid < 64) {
        const float* bb = (m == 0) ? bq : (m == 1) ? bk : bv;
        bias_t[m * 64 + tid] = bb[tid] * scl;
    }
}

// ---------------- kernel 2: QKV projection (v10: 3-ahead DMA) -------------
// 512 blocks x 384 thr = 6 waves (ct 0..5). 32 rows/block, 16 stages.
// 4 LDS buffers, DMA issued 3 stages ahead, B regs 1 ahead, counted vmcnt.
__global__ __launch_bounds__(384, 3) void proj_kernel(
        const float* __restrict__ x, const unsigned short* __restrict__ Wt3,
        const float* __restrict__ bias_t, unsigned short* __restrict__ qs,
        unsigned short* __restrict__ ksf, unsigned short* __restrict__ vtf) {
    __shared__ float Ald[4][2048];   // [buf][32 rows x 64 f32] = 4 x 8 KB

    const int tid = threadIdx.x;
    const int w = tid >> 6, l = tid & 63, g = l >> 5, c32 = l & 31;
    const int ct = w;
    const int rowbase = blockIdx.x * 32;

    const int j1 = w;
    const int row1 = 4 * j1 + (l >> 4);
    const float* gp1 = x + (size_t)(rowbase + row1) * 1024 +
                       (((l & 15) ^ (row1 & 7)) << 2);
    const bool has2 = (w < 2);
    const int j2 = 6 + w;
    const int row2 = 4 * j2 + (l >> 4);
    const float* gp2 = x + (size_t)(rowbase + row2) * 1024 +
                       (((l & 15) ^ (row2 & 7)) << 2);

    const unsigned short* Wb = Wt3 + (size_t)(ct * 4) * 512 + l * 8;

    f32x16 acc = zero16();
    bf16x8 bA[4], bB[4];

    // prologue: DMA stages 0,1,2 -> bufs 0,1,2; B(0) -> bA.
    gload_lds16(gp1, &Ald[0][j1 * 256]);
    if (has2) gload_lds16(gp2, &Ald[0][j2 * 256]);
    gload_lds16(gp1 + 64, &Ald[1][j1 * 256]);
    if (has2) gload_lds16(gp2 + 64, &Ald[1][j2 * 256]);
    gload_lds16(gp1 + 128, &Ald[2][j1 * 256]);
    if (has2) gload_lds16(gp2 + 128, &Ald[2][j2 * 256]);
#pragma unroll
    for (int f = 0; f < 4; ++f) bA[f] = *(const bf16x8*)(Wb + f * 512);
    // need D0 retired; D1,D2,B0 stay in flight: 2c+4
    if (has2) asm volatile("s_waitcnt vmcnt(8)" ::: "memory");
    else      asm volatile("s_waitcnt vmcnt(6)" ::: "memory");
    __builtin_amdgcn_s_barrier();
    __builtin_amdgcn_sched_barrier(0);

    auto STAGE = [&](bf16x8(&bc)[4], bf16x8(&bn)[4], int kt) {
        // (1) B loads for stage kt+1
        if (kt < 15) {
            const unsigned short* Wn = Wb + (size_t)(kt + 1) * 12288;
#pragma unroll
            for (int f = 0; f < 4; ++f) bn[f] = *(const bf16x8*)(Wn + f * 512);
        }
        // (2) DMA stage kt+3 into buf (kt+3)%4 == (kt-1)%4 (readers done
        //     under the PREVIOUS barrier's lgkmcnt(0))
        if (kt < 13) {
            gload_lds16(gp1 + (kt + 3) * 64, &Ald[(kt + 3) & 3][j1 * 256]);
            if (has2)
                gload_lds16(gp2 + (kt + 3) * 64, &Ald[(kt + 3) & 3][j2 * 256]);
        }
        // (3) ds_read fp32 frags (swizzled) + convert + MFMA (bc preloaded)
        const float* A = Ald[kt & 3];
#pragma unroll
        for (int kk = 0; kk < 4; ++kk) {
            const int blk = kk * 4 + g * 2;
            float4 f0 = *(const float4*)(A + c32 * 64 + ((blk ^ (c32 & 7)) << 2));
            float4 f1 = *(const float4*)(A + c32 * 64 + (((blk + 1) ^ (c32 & 7)) << 2));
            uint4v ua;
            ua[0] = cvt2(f0.x, f0.y); ua[1] = cvt2(f0.z, f0.w);
            ua[2] = cvt2(f1.x, f1.y); ua[3] = cvt2(f1.z, f1.w);
            bf16x8 af = __builtin_bit_cast(bf16x8, ua);
            acc = MFMA32(af, bc[kk], acc);
        }
        // (4) counted wait + barrier: prove DMA(kt+1) landed.
        //     #ops issued after D(kt+1): kt<=12: B(kt)+D(kt+2)+B(kt+1)+D(kt+3)
        //     = 2c+8; kt==13: B13+D15+B14 = c+8; kt==14: B14+B15 = 8.
        if (kt <= 12) {
            if (has2) asm volatile("s_waitcnt vmcnt(12) lgkmcnt(0)" ::: "memory");
            else      asm volatile("s_waitcnt vmcnt(10) lgkmcnt(0)" ::: "memory");
            __builtin_amdgcn_s_barrier();
            __builtin_amdgcn_sched_barrier(0);
        } else if (kt == 13) {
            if (has2) asm volatile("s_waitcnt vmcnt(10) lgkmcnt(0)" ::: "memory");
            else      asm volatile("s_waitcnt vmcnt(9) lgkmcnt(0)" ::: "memory");
            __builtin_amdgcn_s_barrier();
            __builtin_amdgcn_sched_barrier(0);
        } else if (kt == 14) {
            asm volatile("s_waitcnt vmcnt(8) lgkmcnt(0)" ::: "memory");
            __builtin_amdgcn_s_barrier();
            __builtin_amdgcn_sched_barrier(0);
        }
        // kt == 15: no barrier (only acc consumed after)
    };

#pragma unroll
    for (int kt = 0; kt < 16; kt += 2) {
        STAGE(bA, bB, kt);
        STAGE(bB, bA, kt + 1);
    }

    const int cg = ct * 32 + c32;
    const float bias = bias_t[cg];
    const int mat = cg >> 6, cm = cg & 63;
    if (mat == 2) {
#pragma unroll
        for (int q4 = 0; q4 < 4; ++q4) {
            const int rowg = rowbase + 8 * q4 + 4 * g;
            const int b = rowg >> 12, tl = rowg & (T_SEQ - 1);
            const int ch = tl >> 5;
            const int f = (cm >> 5) * 2 + (q4 >> 1);
            const int lane = (cm & 31) + 32 * (q4 & 1);
            unsigned lo = cvt2(acc[4 * q4 + 0] + bias, acc[4 * q4 + 1] + bias);
            unsigned hi = cvt2(acc[4 * q4 + 2] + bias, acc[4 * q4 + 3] + bias);
            *(uint2*)(vtf + ((size_t)b * 128 + ch) * 2048 + f * 512 +
                      lane * 8 + 4 * g) = make_uint2(lo, hi);
        }
    } else if (mat == 1) {
#pragma unroll
        for (int r = 0; r < 16; ++r) {
            const int rowg = rowbase + (r & 3) + 8 * (r >> 2) + 4 * g;
            const int b = rowg >> 12, tl = rowg & (T_SEQ - 1);
            ksf[((size_t)b * 128 + (tl >> 5)) * 2048 + (cm >> 4) * 512 +
                ((tl & 31) + 32 * ((cm >> 3) & 1)) * 8 + (cm & 7)] =
                bf1(acc[r] + bias);
        }
    } else {
#pragma unroll
        for (int r = 0; r < 16; ++r) {
            const int rowg = rowbase + (r & 3) + 8 * (r >> 2) + 4 * g;
            qs[(size_t)rowg * 64 + cm] = bf1(acc[r] + bias);
        }
    }
}

// ---------------- kernel 3: causal flash attention (R24 verbatim) ---------
__global__ __launch_bounds__(512, 2) void attn_kernel(
        const unsigned short* __restrict__ qs, const unsigned short* __restrict__ ksf,
        const unsigned short* __restrict__ vtf, float* __restrict__ out) {
    __shared__ unsigned short Osh[NW][32][66];
    __shared__ float msh[NW][32];
    __shared__ float ssh[NW][32];

    const int tid = threadIdx.x;
    const int w = tid >> 6, l = tid & 63, g = l >> 5, c32 = l & 31;
    const int b = blockIdx.x & 3;
    const int pid = blockIdx.x >> 2;

    for (int tt = 0; tt < 2; ++tt) {
        const int jt = tt ? pid : 127 - pid;
        const int qbase = jt * 32;

        const unsigned short* qp =
            qs + ((size_t)b * T_SEQ + qbase + c32) * 64 + g * 8;
        bf16x8 qf[4];
#pragma unroll
        for (int t = 0; t < 4; ++t) qf[t] = *(const bf16x8*)(qp + 16 * t);

        const unsigned short* pKc = ksf + ((size_t)b * 128 + w) * 2048 + l * 8;
        const unsigned short* pVc = vtf + ((size_t)b * 128 + w) * 2048 + l * 8;

        const int nch = (jt >= w) ? (jt - w) / NW + 1 : 0;
        const bool hasDiag = (jt >= w) && ((jt - w) % NW == 0);
        const int npair = nch >> 1;
        const bool tailOdd = (nch & 1) != 0;
        float m = -INFINITY, ssum = 0.0f;
        f32x16 o0 = zero16(), o1 = zero16();

        auto LOADK = [&](bf16x8(&kA)[4], bf16x8(&kB)[4]) {
#pragma unroll
            for (int t = 0; t < 4; ++t) {
                kA[t] = *(const bf16x8*)(pKc + t * 512);
                kB[t] = *(const bf16x8*)(pKc + NW * 2048 + t * 512);
            }
            pKc += 2 * NW * 2048;
        };
        auto DEFER = [&](float pm) {
            if (!__all(pm <= m + 8.0f)) {
                float rmax = fmaxf(pm, __shfl_xor(pm, 32, 64));
                const float mn = fmaxf(m, rmax);
                const float alpha = exp2f(m - mn);
#pragma unroll
                for (int r = 0; r < 16; ++r) { o0[r] *= alpha; o1[r] *= alpha; }
                ssum *= alpha;
                m = mn;
            }
        };
        auto TREEMAX = [&](const f32x16& s) {
            float a0 = fmaxf(fmaxf(s[0], s[1]), fmaxf(s[2], s[3]));
            float a1 = fmaxf(fmaxf(s[4], s[5]), fmaxf(s[6], s[7]));
            float a2 = fmaxf(fmaxf(s[8], s[9]), fmaxf(s[10], s[11]));
            float a3 = fmaxf(fmaxf(s[12], s[13]), fmaxf(s[14], s[15]));
            return fmaxf(fmaxf(a0, a1), fmaxf(a2, a3));
        };
        auto EXPPACK = [&](const f32x16& s, bf16x8& pb0, bf16x8& pb1) {
            float p[16];
#pragma unroll
            for (int r = 0; r < 16; ++r) p[r] = exp2f(s[r] - m);
            float s0 = (p[0] + p[1]) + (p[2] + p[3]);
            float s1 = (p[4] + p[5]) + (p[6] + p[7]);
            float s2 = (p[8] + p[9]) + (p[10] + p[11]);
            float s3 = (p[12] + p[13]) + (p[14] + p[15]);
            ssum += (s0 + s1) + (s2 + s3);
            unsigned c01 = cvt2(p[0], p[1]), c23 = cvt2(p[2], p[3]);
            unsigned c45 = cvt2(p[4], p[5]), c67 = cvt2(p[6], p[7]);
            pswap(c01, c45); pswap(c23, c67);
            unsigned c89 = cvt2(p[8], p[9]), cab = cvt2(p[10], p[11]);
            unsigned ccd = cvt2(p[12], p[13]), cef = cvt2(p[14], p[15]);
            pswap(c89, ccd); pswap(cab, cef);
            uint4v u0; u0[0] = c01; u0[1] = c23; u0[2] = c45; u0[3] = c67;
            uint4v u1; u1[0] = c89; u1[1] = cab; u1[2] = ccd; u1[3] = cef;
            pb0 = __builtin_bit_cast(bf16x8, u0);
            pb1 = __builtin_bit_cast(bf16x8, u1);
        };

        bf16x8 kA0[4], kB0[4], kA1[4], kB1[4];   // K pair double-buffer
        if (npair > 0) LOADK(kA0, kB0);

        auto PAIR = [&](bf16x8(&kA)[4], bf16x8(&kB)[4],
                        bf16x8(&nkA)[4], bf16x8(&nkB)[4], int j) {
            bf16x8 vA[4], vB[4];
#pragma unroll
            for (int f = 0; f < 4; ++f) {
                vA[f] = *(const bf16x8*)(pVc + f * 512);
                vB[f] = *(const bf16x8*)(pVc + NW * 2048 + f * 512);
            }
            pVc += 2 * NW * 2048;
            f32x16 sa = zero16(), sb = zero16();
            __builtin_amdgcn_s_setprio(1);
#pragma unroll
            for (int t = 0; t < 4; ++t) {
                sa = MFMA32(kA[t], qf[t], sa);
                sb = MFMA32(kB[t], qf[t], sb);
            }
            __builtin_amdgcn_s_setprio(0);
            if (j + 1 < npair) LOADK(nkA, nkB);
            if (hasDiag && !tailOdd && j == npair - 1) {
#pragma unroll
                for (int r = 0; r < 16; ++r) {
                    const int kl = (r & 3) + 8 * (r >> 2) + 4 * g;
                    if (kl > c32) sb[r] = -1e30f;
                }
            }
            DEFER(fmaxf(TREEMAX(sa), TREEMAX(sb)));
            bf16x8 pa0, pa1, pb0, pb1;
            EXPPACK(sa, pa0, pa1);
            EXPPACK(sb, pb0, pb1);
            __builtin_amdgcn_s_setprio(1);
            o0 = MFMA32(vA[0], pa0, o0);
            o1 = MFMA32(vA[2], pa0, o1);
            o0 = MFMA32(vA[1], pa1, o0);
            o1 = MFMA32(vA[3], pa1, o1);
            o0 = MFMA32(vB[0], pb0, o0);
            o1 = MFMA32(vB[2], pb0, o1);
            o0 = MFMA32(vB[1], pb1, o0);
            o1 = MFMA32(vB[3], pb1, o1);
            __builtin_amdgcn_s_setprio(0);
        };

        int j = 0;
        while (j < npair) {
            PAIR(kA0, kB0, kA1, kB1, j); ++j;
            if (j < npair) { PAIR(kA1, kB1, kA0, kB0, j); ++j; }
        }
        if (tailOdd) {
            bf16x8 kT[4], vT[4];
#pragma unroll
            for (int t = 0; t < 4; ++t) kT[t] = *(const bf16x8*)(pKc + t * 512);
#pragma unroll
            for (int f = 0; f < 4; ++f) vT[f] = *(const bf16x8*)(pVc + f * 512);
            f32x16 sa = zero16();
            __builtin_amdgcn_s_setprio(1);
#pragma unroll
            for (int t = 0; t < 4; ++t) sa = MFMA32(kT[t], qf[t], sa);
            __builtin_amdgcn_s_setprio(0);
            if (hasDiag) {
#pragma unroll
                for (int r = 0; r < 16; ++r) {
                    const int kl = (r & 3) + 8 * (r >> 2) + 4 * g;
                    if (kl > c32) sa[r] = -1e30f;
                }
            }
            DEFER(TREEMAX(sa));
            bf16x8 pa0, pa1;
            EXPPACK(sa, pa0, pa1);
            __builtin_amdgcn_s_setprio(1);
            o0 = MFMA32(vT[0], pa0, o0);
            o1 = MFMA32(vT[2], pa0, o1);
            o0 = MFMA32(vT[1], pa1, o0);
            o1 = MFMA32(vT[3], pa1, o1);
            __builtin_amdgcn_s_setprio(0);
        }
        ssum += __shfl_xor(ssum, 32, 64);

        if (l < 32) { msh[w][l] = m; ssh[w][l] = ssum; }
#pragma unroll
        for (int q4 = 0; q4 < 4; ++q4) {
            const int base = 8 * q4 + 4 * g;
            *(unsigned*)&Osh[w][c32][base]      = cvt2(o0[4 * q4], o0[4 * q4 + 1]);
            *(unsigned*)&Osh[w][c32][base + 2]  = cvt2(o0[4 * q4 + 2], o0[4 * q4 + 3]);
            *(unsigned*)&Osh[w][c32][base + 32] = cvt2(o1[4 * q4], o1[4 * q4 + 1]);
            *(unsigned*)&Osh[w][c32][base + 34] = cvt2(o1[4 * q4 + 2], o1[4 * q4 + 3]);
        }
        __syncthreads();

        {   // combine NW wave-partials (512 thr: 32 rows x 16 d-quads)
            const int qrow = tid >> 4, e4 = tid & 15;
            float M = -INFINITY;
            float mw[NW];
#pragma unroll
            for (int u = 0; u < NW; ++u) { mw[u] = msh[u][qrow]; M = fmaxf(M, mw[u]); }
            float den = 0.0f;
            float r0 = 0.f, r1 = 0.f, r2 = 0.f, r3 = 0.f;
#pragma unroll
            for (int u = 0; u < NW; ++u) {
                const float scu = exp2f(mw[u] - M);
                den += ssh[u][qrow] * scu;
                const unsigned ua = *(const unsigned*)&Osh[u][qrow][4 * e4];
                const unsigned ub = *(const unsigned*)&Osh[u][qrow][4 * e4 + 2];
                r0 += bflo(ua) * scu;
                r1 += bfhi(ua) * scu;
                r2 += bflo(ub) * scu;
                r3 += bfhi(ub) * scu;
            }
            const float inv = 1.0f / den;
            float4 st;
            st.x = r0 * inv; st.y = r1 * inv; st.z = r2 * inv; st.w = r3 * inv;
            *(float4*)(out + ((size_t)b * T_SEQ + qbase + qrow) * 64 + 4 * e4) = st;
        }
        __syncthreads();
    }
}

// ---------------- launch ----------------
extern "C" void kernel_launch(void* const* d_in, const int* in_sizes, int n_in,
                              void* d_out, int out_size, void* d_ws, size_t ws_size,
                              hipStream_t stream) {
    const float* x  = (const float*)d_in[0];
    const float* Wq = (const float*)d_in[1];
    const float* bq = (const float*)d_in[2];
    const float* Wk = (const float*)d_in[3];
    const float* bk = (const float*)d_in[4];
    const float* Wv = (const float*)d_in[5];
    const float* bv = (const float*)d_in[6];
    float* out = (float*)d_out;

    char* ws = (char*)d_ws;
    unsigned short* Wt3    = (unsigned short*)(ws);                 // 384 KB
    float*          bias_t = (float*)(ws + 393216);                 // 768 B
    unsigned short* qsb    = (unsigned short*)(ws + (1u << 20));    // 2 MB
    unsigned short* ksb    = (unsigned short*)(ws + (3u << 20));    // 2 MB
    unsigned short* vtb    = (unsigned short*)(ws + (5u << 20));    // 2 MB

    prep_w<<<48, 256, 0, stream>>>(Wq, Wk, Wv, bq, bk, bv, Wt3, bias_t);
    proj_kernel<<<512, 384, 0, stream>>>(x, Wt3, bias_t, qsb, ksb, vtb);
    attn_kernel<<<256, 512, 0, stream>>>(qsb, ksb, vtb, out);
}